// Round 2
// baseline (2253.939 us; speedup 1.0000x reference)
//
#include <hip/hip_runtime.h>
#include <math.h>

#define Bn   8
#define Cn   256
#define HWn  4096
#define FB   (Cn * HWn)      // 1048576 floats per batch-field
#define NTOT (Bn * FB)       // 8388608 floats per field (32 MiB)
#define TEND 1.0
#define EPSK 1e-12f

static __host__ __device__ inline int slot_jk(int j, int k) { return k * (k + 1) / 2 + j; }

// ---------------- zero the small stats region ----------------
__global__ void init_kernel(float* __restrict__ p) {
    // zero acc (512) + Hb (576) = 1088 floats
    for (int i = threadIdx.x; i < 1088; i += 256) p[i] = 0.0f;
}

// ---------------- transpose W (256x256) -> Wt[c][o] ----------------
__global__ void transpose_kernel(const float* __restrict__ W, float* __restrict__ Wt) {
    int o = blockIdx.x, c = threadIdx.x;
    Wt[c * 256 + o] = W[o * 256 + c];
}

// ---------------- dot: acc[b] += scale_a * sum(a*b) ----------------
__global__ __launch_bounds__(256) void dot_kernel(const float* __restrict__ a,
                                                  const float* __restrict__ bsrc,
                                                  float* __restrict__ accDst,
                                                  const float* __restrict__ nAcc) {
    int b = blockIdx.y;
    const float4* av = (const float4*)(a + (size_t)b * FB);
    const float4* bv = (const float4*)(bsrc + (size_t)b * FB);
    int i = blockIdx.x * 256 + threadIdx.x;
    float p = 0.f;
#pragma unroll
    for (int r = 0; r < 4; ++r) {
        float4 x = av[i + r * 65536];
        float4 y = bv[i + r * 65536];
        p = fmaf(x.x, y.x, p); p = fmaf(x.y, y.y, p);
        p = fmaf(x.z, y.z, p); p = fmaf(x.w, y.w, p);
    }
    for (int off = 32; off > 0; off >>= 1) p += __shfl_down(p, off);
    __shared__ float red[4];
    int lane = threadIdx.x & 63, wid = threadIdx.x >> 6;
    if (lane == 0) red[wid] = p;
    __syncthreads();
    if (threadIdx.x == 0) {
        float val = red[0] + red[1] + red[2] + red[3];
        if (nAcc != nullptr) val *= (1.0f / sqrtf(nAcc[b]));
        atomicAdd(&accDst[b], val);
    }
}

// -------- fused: w -= (h*scale_prev)*qprev;  acc[b] += sum(qj * w_new); hdst = h --------
__global__ __launch_bounds__(256) void axpy_dot_kernel(float* __restrict__ w,
                                                       const float* __restrict__ qprev,
                                                       const float* __restrict__ qj,
                                                       const float* __restrict__ hsrc,
                                                       float* __restrict__ hdst,
                                                       float* __restrict__ accDst,
                                                       const float* __restrict__ nAccP) {
    int b = blockIdx.y;
    float h = hsrc[b];
    float hq = (nAccP != nullptr) ? h * (1.0f / sqrtf(nAccP[b])) : h;
    if (hdst != nullptr && blockIdx.x == 0 && threadIdx.x == 0) hdst[b * 72] = h;
    float4* wv = (float4*)(w + (size_t)b * FB);
    const float4* pv = (const float4*)(qprev + (size_t)b * FB);
    const float4* jv = (const float4*)(qj + (size_t)b * FB);
    int i = blockIdx.x * 256 + threadIdx.x;
    float p = 0.f;
#pragma unroll
    for (int r = 0; r < 4; ++r) {
        int idx = i + r * 65536;
        float4 x = wv[idx];
        float4 q = pv[idx];
        float4 jq = jv[idx];
        x.x = fmaf(-hq, q.x, x.x); x.y = fmaf(-hq, q.y, x.y);
        x.z = fmaf(-hq, q.z, x.z); x.w = fmaf(-hq, q.w, x.w);
        wv[idx] = x;
        p = fmaf(jq.x, x.x, p); p = fmaf(jq.y, x.y, p);
        p = fmaf(jq.z, x.z, p); p = fmaf(jq.w, x.w, p);
    }
    for (int off = 32; off > 0; off >>= 1) p += __shfl_down(p, off);
    __shared__ float red[4];
    int lane = threadIdx.x & 63, wid = threadIdx.x >> 6;
    if (lane == 0) red[wid] = p;
    __syncthreads();
    if (threadIdx.x == 0) atomicAdd(&accDst[b], red[0] + red[1] + red[2] + red[3]);
}

// -------- fused: w -= (h*scale_prev)*qprev;  acc[b] += sum(w_new^2); hdst = h --------
__global__ __launch_bounds__(256) void axpy_norm_kernel(float* __restrict__ w,
                                                        const float* __restrict__ qprev,
                                                        const float* __restrict__ hsrc,
                                                        float* __restrict__ hdst,
                                                        float* __restrict__ accDst,
                                                        const float* __restrict__ nAccP) {
    int b = blockIdx.y;
    float h = hsrc[b];
    float hq = (nAccP != nullptr) ? h * (1.0f / sqrtf(nAccP[b])) : h;
    if (hdst != nullptr && blockIdx.x == 0 && threadIdx.x == 0) hdst[b * 72] = h;
    float4* wv = (float4*)(w + (size_t)b * FB);
    const float4* pv = (const float4*)(qprev + (size_t)b * FB);
    int i = blockIdx.x * 256 + threadIdx.x;
    float p = 0.f;
#pragma unroll
    for (int r = 0; r < 4; ++r) {
        int idx = i + r * 65536;
        float4 x = wv[idx];
        float4 q = pv[idx];
        x.x = fmaf(-hq, q.x, x.x); x.y = fmaf(-hq, q.y, x.y);
        x.z = fmaf(-hq, q.z, x.z); x.w = fmaf(-hq, q.w, x.w);
        wv[idx] = x;
        p = fmaf(x.x, x.x, p); p = fmaf(x.y, x.y, p);
        p = fmaf(x.z, x.z, p); p = fmaf(x.w, x.w, p);
    }
    for (int off = 32; off > 0; off >>= 1) p += __shfl_down(p, off);
    __shared__ float red[4];
    int lane = threadIdx.x & 63, wid = threadIdx.x >> 6;
    if (lane == 0) red[wid] = p;
    __syncthreads();
    if (threadIdx.x == 0) atomicAdd(&accDst[b], red[0] + red[1] + red[2] + red[3]);
}

// ---------------- dst = src / (sqrt(acc) + eps); hdst = sqrt(acc) ----------------
__global__ __launch_bounds__(256) void normalize_kernel(const float* __restrict__ src,
                                                        float* __restrict__ dst,
                                                        const float* __restrict__ accSrc,
                                                        float* __restrict__ hdst, float eps) {
    int b = blockIdx.y;
    float nrm = sqrtf(accSrc[b]);
    float s = 1.0f / (nrm + eps);
    if (hdst != nullptr && blockIdx.x == 0 && threadIdx.x == 0) hdst[b * 72] = nrm;
    const float4* sv = (const float4*)(src + (size_t)b * FB);
    float4* dv = (float4*)(dst + (size_t)b * FB);
    int i = blockIdx.x * 256 + threadIdx.x;
#pragma unroll
    for (int r = 0; r < 4; ++r) {
        int idx = i + r * 65536;
        float4 x = sv[idx];
        x.x *= s; x.y *= s; x.z *= s; x.w *= s;
        dv[idx] = x;
    }
}

// ------- apply A: out = W @ (s0*(x*sca) - s0*colsum(s0*(x*sca))) per 64-pos tile -------
__global__ __launch_bounds__(256) void apply_A_kernel(const float* __restrict__ x,
                                                      const float* __restrict__ s0,
                                                      const float* __restrict__ Wt,
                                                      float* __restrict__ outw,
                                                      const float* __restrict__ nAcc) {
    __shared__ float sx[256][64];   // 64 KB
    __shared__ float tsum[4][64];
    __shared__ float tcol[64];
    const int tid = threadIdx.x;
    const int b = blockIdx.y;
    const float sca = (nAcc != nullptr) ? (1.0f / sqrtf(nAcc[b])) : 1.0f;
    const int sbase = blockIdx.x * 64;
    const float* xb  = x  + (size_t)b * FB;
    const float* s0b = s0 + (size_t)b * FB;
    float*       ob  = outw + (size_t)b * FB;

    const int cq = tid >> 4;         // 0..15
    const int sp = (tid & 15) * 4;   // 0..60
    float4 s0v[16];
#pragma unroll
    for (int r = 0; r < 16; ++r) {
        int c = r * 16 + cq;
        float4 xv = *(const float4*)(xb  + (size_t)c * HWn + sbase + sp);
        float4 sv = *(const float4*)(s0b + (size_t)c * HWn + sbase + sp);
        s0v[r] = sv;
        float4 m;
        m.x = sv.x * (xv.x * sca); m.y = sv.y * (xv.y * sca);
        m.z = sv.z * (xv.z * sca); m.w = sv.w * (xv.w * sca);
        *(float4*)(&sx[c][sp]) = m;
    }
    __syncthreads();
    {
        const int s = tid & 63;
        const int g = tid >> 6;
        float p = 0.f;
#pragma unroll 8
        for (int c = g * 64; c < g * 64 + 64; ++c) p += sx[c][s];
        tsum[g][s] = p;
    }
    __syncthreads();
    if (tid < 64) tcol[tid] = tsum[0][tid] + tsum[1][tid] + tsum[2][tid] + tsum[3][tid];
    __syncthreads();
    {
        float t0 = tcol[sp], t1 = tcol[sp + 1], t2 = tcol[sp + 2], t3 = tcol[sp + 3];
#pragma unroll
        for (int r = 0; r < 16; ++r) {
            int c = r * 16 + cq;
            float4 cur = *(float4*)(&sx[c][sp]);
            cur.x -= s0v[r].x * t0; cur.y -= s0v[r].y * t1;
            cur.z -= s0v[r].z * t2; cur.w -= s0v[r].w * t3;
            *(float4*)(&sx[c][sp]) = cur;
        }
    }
    __syncthreads();
    // GEMM: out[o][s] = sum_c Wt[c][o] * y[c][s], 8x8 per thread
    const int tx = tid & 31;  // o block
    const int ty = tid >> 5;  // s block
    float acc[8][8] = {};
    const float* wp = Wt + tx * 8;
#pragma unroll 2
    for (int c = 0; c < 256; ++c) {
        float4 w0 = *(const float4*)(wp + c * 256);
        float4 w1 = *(const float4*)(wp + c * 256 + 4);
        float4 y0 = *(const float4*)(&sx[c][ty * 8]);
        float4 y1 = *(const float4*)(&sx[c][ty * 8 + 4]);
        float wv[8] = {w0.x, w0.y, w0.z, w0.w, w1.x, w1.y, w1.z, w1.w};
        float yv[8] = {y0.x, y0.y, y0.z, y0.w, y1.x, y1.y, y1.z, y1.w};
#pragma unroll
        for (int i = 0; i < 8; ++i)
#pragma unroll
            for (int j = 0; j < 8; ++j)
                acc[i][j] = fmaf(wv[i], yv[j], acc[i][j]);
    }
#pragma unroll
    for (int i = 0; i < 8; ++i) {
        float4 r0 = {acc[i][0], acc[i][1], acc[i][2], acc[i][3]};
        float4 r1 = {acc[i][4], acc[i][5], acc[i][6], acc[i][7]};
        float* dst = ob + (size_t)(tx * 8 + i) * HWn + sbase + ty * 8;
        *(float4*)dst = r0;
        *(float4*)(dst + 4) = r1;
    }
}

// ---------------- expm of 9x9 per batch (fp64, scaling+squaring, Horner Taylor) --------
// coords[b*8+0] = expm[0,8] (no vnorm); coords[b*8+j] = expm[j,8] * vnorm for j>=1.
__global__ __launch_bounds__(128) void expm_kernel(const float* __restrict__ Hbuf,
                                                   const float* __restrict__ acc,
                                                   float* __restrict__ coordsOut) {
    __shared__ double Am[81], Pm[81], Tm[81];
    __shared__ double ssc;
    __shared__ int sn;
    const int b = blockIdx.x;
    const int t = threadIdx.x;
    const int r = t / 9, c = t % 9;
    if (t < 81) {
        double v = 0.0;
        if (r < 8 && c < 8) v = TEND * (double)Hbuf[b * 72 + r * 8 + c];
        if (r == 7 && c == 7) v = TEND * (double)acc[35 * 8 + b];  // h_{7,7} never copied to Hb
        if (r == 0 && c == 8) v = TEND;
        Am[t] = v;
    }
    __syncthreads();
    if (t == 0) {
        double mx = 0.0;
        for (int rr = 0; rr < 9; ++rr) {
            double s = 0.0;
            for (int cc = 0; cc < 9; ++cc) s += fabs(Am[rr * 9 + cc]);
            if (s > mx) mx = s;
        }
        int n = 0;
        while (mx > 0.25 && n < 48) { mx *= 0.5; ++n; }
        double sc = 1.0;
        for (int ii = 0; ii < n; ++ii) sc *= 0.5;
        sn = n; ssc = sc;
    }
    __syncthreads();
    if (t < 81) Am[t] *= ssc;
    __syncthreads();
    if (t < 81) Pm[t] = (r == c) ? 1.0 : 0.0;
    __syncthreads();
    for (int i = 20; i >= 1; --i) {
        if (t < 81) {
            double s = 0.0;
            for (int k = 0; k < 9; ++k) s += Am[r * 9 + k] * Pm[k * 9 + c];
            Tm[t] = ((r == c) ? 1.0 : 0.0) + s / (double)i;
        }
        __syncthreads();
        if (t < 81) Pm[t] = Tm[t];
        __syncthreads();
    }
    int n = sn;
    for (int q = 0; q < n; ++q) {
        if (t < 81) {
            double s = 0.0;
            for (int k = 0; k < 9; ++k) s += Pm[r * 9 + k] * Pm[k * 9 + c];
            Tm[t] = s;
        }
        __syncthreads();
        if (t < 81) Pm[t] = Tm[t];
        __syncthreads();
    }
    if (t < 8) {
        double vn = sqrt((double)acc[44 * 8 + b]);
        double val = Pm[t * 9 + 8];
        if (t > 0) val *= vn;
        coordsOut[b * 8 + t] = (float)val;
    }
}

// ------ out = coords[0]*v + sum_{j=1..7} coords[j] * Q_{j} (Q_j at Qb+(j-1)*NTOT) ------
__global__ __launch_bounds__(256) void combine_kernel(const float* __restrict__ Qb,
                                                      const float* __restrict__ v,
                                                      const float* __restrict__ coords,
                                                      float* __restrict__ out) {
    int b = blockIdx.y;
    float cf[8];
#pragma unroll
    for (int j = 0; j < 8; ++j) cf[j] = coords[b * 8 + j];
    int i = blockIdx.x * 256 + threadIdx.x;
    float4* ov = (float4*)(out + (size_t)b * FB);
    const float4* vv = (const float4*)(v + (size_t)b * FB);
#pragma unroll
    for (int r = 0; r < 4; ++r) {
        int idx = i + r * 65536;
        float4 q0 = vv[idx];
        float4 a;
        a.x = cf[0] * q0.x; a.y = cf[0] * q0.y;
        a.z = cf[0] * q0.z; a.w = cf[0] * q0.w;
#pragma unroll
        for (int j = 1; j < 8; ++j) {
            const float4* qv = (const float4*)(Qb + (size_t)(j - 1) * NTOT + (size_t)b * FB);
            float4 q = qv[idx];
            a.x = fmaf(cf[j], q.x, a.x); a.y = fmaf(cf[j], q.y, a.y);
            a.z = fmaf(cf[j], q.z, a.z); a.w = fmaf(cf[j], q.w, a.w);
        }
        ov[idx] = a;
    }
}

extern "C" void kernel_launch(void* const* d_in, const int* in_sizes, int n_in,
                              void* d_out, int out_size, void* d_ws, size_t ws_size,
                              hipStream_t stream) {
    const float* s0 = (const float*)d_in[0];
    const float* v  = (const float*)d_in[1];
    const float* W  = (const float*)d_in[2];
    float* out = (float*)d_out;

    // ws layout (floats): [acc 512 | Hb 576 | coords 64 | Wt 65536 | Q1..Q7 7*NTOT]
    // total = 66688 + 7*8388608 = 58,786,944 floats = ~224.3 MiB
    float* ws     = (float*)d_ws;
    float* acc    = ws;                 // 512 floats (slot x 8 batches)
    float* Hb     = ws + 512;           // 576 floats (8 batches x 9r x 8c)
    float* coords = ws + 1088;          // 64 floats
    float* Wt     = ws + 1152;          // 65536 floats
    float* Q      = ws + 66688;         // Q_j (j=1..7) at Q + (j-1)*NTOT
    float* w      = out;                // reuse d_out as working vector
    float* vnAcc  = acc + 44 * 8;       // ||v||^2 per batch

    init_kernel<<<dim3(1), dim3(256), 0, stream>>>(ws);
    transpose_kernel<<<dim3(256), dim3(256), 0, stream>>>(W, Wt);

    dim3 g(256, 8), blk(256);
    // vnorm^2 = <v,v>  (Q0 = v/vnorm is never materialized; scale folded into consumers)
    dot_kernel<<<g, blk, 0, stream>>>(v, v, vnAcc, nullptr);

    for (int k = 0; k < 8; ++k) {
        const float* xk = (k == 0) ? v : (Q + (size_t)(k - 1) * NTOT);
        const float* nX = (k == 0) ? vnAcc : nullptr;
        apply_A_kernel<<<dim3(64, 8), blk, 0, stream>>>(xk, s0, Wt, w, nX);
        // h_{0,k} = <Q0, w> = <v,w>/vnorm
        dot_kernel<<<g, blk, 0, stream>>>(v, w, acc + slot_jk(0, k) * 8, vnAcc);
        for (int j = 1; j <= k; ++j) {
            const float* qprev = (j == 1) ? v : (Q + (size_t)(j - 2) * NTOT);
            const float* nP    = (j == 1) ? vnAcc : nullptr;
            axpy_dot_kernel<<<g, blk, 0, stream>>>(w, qprev,
                                                   Q + (size_t)(j - 1) * NTOT,
                                                   acc + slot_jk(j - 1, k) * 8,
                                                   Hb + ((j - 1) * 8 + k),
                                                   acc + slot_jk(j, k) * 8, nP);
        }
        if (k < 7) {
            const float* qprev = (k == 0) ? v : (Q + (size_t)(k - 1) * NTOT);
            const float* nP    = (k == 0) ? vnAcc : nullptr;
            axpy_norm_kernel<<<g, blk, 0, stream>>>(w, qprev,
                                                    acc + slot_jk(k, k) * 8,
                                                    Hb + (k * 8 + k),
                                                    acc + (36 + k) * 8, nP);
            normalize_kernel<<<g, blk, 0, stream>>>(w, Q + (size_t)k * NTOT,
                                                    acc + (36 + k) * 8,
                                                    Hb + ((k + 1) * 8 + k), EPSK);
        }
    }

    expm_kernel<<<dim3(8), dim3(128), 0, stream>>>(Hb, acc, coords);
    combine_kernel<<<g, blk, 0, stream>>>(Q, v, coords, out);
}

// Round 3
// 1609.189 us; speedup vs baseline: 1.4007x; 1.4007x over previous
//
#include <hip/hip_runtime.h>
#include <math.h>

#define Bn   8
#define Cn   256
#define HWn  4096
#define FB   (Cn * HWn)      // 1048576 floats per batch-field
#define NTOT (Bn * FB)       // 8388608 floats per field (32 MiB)
#define TEND 1.0
#define EPSK 1e-12f
#define TILE_S 32

// acc layout (floats, 8 batches each):
//   dots[k][j] at acc[(k*8+j)*8 + b]   (k,j in 0..7)  -> 512 floats
//   nsq[j]     at acc[512 + j*8 + b]                  -> 64 floats
// coords at acc+576 (64 floats)

// ---------------- zero the small stats region ----------------
__global__ void init_kernel(float* __restrict__ p) {
    for (int i = threadIdx.x; i < 1024; i += 256) p[i] = 0.0f;
}

// ---------------- transpose W (256x256) -> Wt[c][o] ----------------
__global__ void transpose_kernel(const float* __restrict__ W, float* __restrict__ Wt) {
    int o = blockIdx.x, c = threadIdx.x;
    Wt[c * 256 + o] = W[o * 256 + c];
}

// ---------------- nsq[0][b] += sum(v*v) ----------------
__global__ __launch_bounds__(256) void norm0_kernel(const float* __restrict__ v,
                                                    float* __restrict__ acc) {
    int b = blockIdx.y;
    const float4* av = (const float4*)(v + (size_t)b * FB);
    int i = blockIdx.x * 256 + threadIdx.x;
    float p = 0.f;
#pragma unroll
    for (int r = 0; r < 4; ++r) {
        float4 x = av[i + r * 65536];
        p = fmaf(x.x, x.x, p); p = fmaf(x.y, x.y, p);
        p = fmaf(x.z, x.z, p); p = fmaf(x.w, x.w, p);
    }
    for (int off = 32; off > 0; off >>= 1) p += __shfl_down(p, off);
    __shared__ float red[4];
    int lane = threadIdx.x & 63, wid = threadIdx.x >> 6;
    if (lane == 0) red[wid] = p;
    __syncthreads();
    if (threadIdx.x == 0) atomicAdd(&acc[512 + b], red[0] + red[1] + red[2] + red[3]);
}

// -------- dots pass (CGS): d_j = <U_j, w> raw, j=0..k, single read of w --------
__global__ __launch_bounds__(256) void dots_kernel(const float* __restrict__ w,
                                                   const float* __restrict__ v,
                                                   const float* __restrict__ Qb,
                                                   float* __restrict__ acc, int k) {
    int b = blockIdx.y;
    const float4* wv = (const float4*)(w + (size_t)b * FB);
    int i = blockIdx.x * 256 + threadIdx.x;
    float p[8] = {0.f, 0.f, 0.f, 0.f, 0.f, 0.f, 0.f, 0.f};
#pragma unroll
    for (int r = 0; r < 4; ++r) {
        int idx = i + r * 65536;
        float4 x = wv[idx];
#pragma unroll
        for (int j = 0; j < 8; ++j) {
            if (j <= k) {
                const float* U = (j == 0) ? v : (Qb + (size_t)(j - 1) * NTOT);
                float4 u = ((const float4*)(U + (size_t)b * FB))[idx];
                p[j] = fmaf(u.x, x.x, p[j]); p[j] = fmaf(u.y, x.y, p[j]);
                p[j] = fmaf(u.z, x.z, p[j]); p[j] = fmaf(u.w, x.w, p[j]);
            }
        }
    }
    __shared__ float red[4][8];
    int lane = threadIdx.x & 63, wid = threadIdx.x >> 6;
#pragma unroll
    for (int j = 0; j < 8; ++j) {
        if (j <= k) {
            float q = p[j];
            for (int off = 32; off > 0; off >>= 1) q += __shfl_down(q, off);
            if (lane == 0) red[wid][j] = q;
        }
    }
    __syncthreads();
    if (threadIdx.x < 8 && (int)threadIdx.x <= k)
        atomicAdd(&acc[(k * 8 + threadIdx.x) * 8 + b],
                  red[0][threadIdx.x] + red[1][threadIdx.x] +
                  red[2][threadIdx.x] + red[3][threadIdx.x]);
}

// -------- CGS update: U_k = w - sum_j (d_j/(n_j+e)^2) U_j;  nsq[k] += ||U_k||^2 --------
__global__ __launch_bounds__(256) void update_kernel(const float* __restrict__ w,
                                                     const float* __restrict__ v,
                                                     float* __restrict__ Qb,
                                                     float* __restrict__ acc, int k) {
    int b = blockIdx.y;
    float cj[8];
#pragma unroll
    for (int j = 0; j < 8; ++j) {
        if (j < k) {
            float d  = acc[((k - 1) * 8 + j) * 8 + b];
            float n2 = acc[512 + j * 8 + b];
            float nn = sqrtf(n2) + ((j == 0) ? 0.f : EPSK);
            cj[j] = d / (nn * nn);
        } else cj[j] = 0.f;
    }
    const float4* wv = (const float4*)(w + (size_t)b * FB);
    float4* Uk = (float4*)(Qb + (size_t)(k - 1) * NTOT + (size_t)b * FB);
    int i = blockIdx.x * 256 + threadIdx.x;
    float p = 0.f;
#pragma unroll
    for (int r = 0; r < 4; ++r) {
        int idx = i + r * 65536;
        float4 x = wv[idx];
#pragma unroll
        for (int j = 0; j < 8; ++j) {
            if (j < k) {
                const float* U = (j == 0) ? v : (Qb + (size_t)(j - 1) * NTOT);
                float4 u = ((const float4*)(U + (size_t)b * FB))[idx];
                x.x = fmaf(-cj[j], u.x, x.x); x.y = fmaf(-cj[j], u.y, x.y);
                x.z = fmaf(-cj[j], u.z, x.z); x.w = fmaf(-cj[j], u.w, x.w);
            }
        }
        Uk[idx] = x;
        p = fmaf(x.x, x.x, p); p = fmaf(x.y, x.y, p);
        p = fmaf(x.z, x.z, p); p = fmaf(x.w, x.w, p);
    }
    for (int off = 32; off > 0; off >>= 1) p += __shfl_down(p, off);
    __shared__ float red[4];
    int lane = threadIdx.x & 63, wid = threadIdx.x >> 6;
    if (lane == 0) red[wid] = p;
    __syncthreads();
    if (threadIdx.x == 0)
        atomicAdd(&acc[512 + k * 8 + b], red[0] + red[1] + red[2] + red[3]);
}

// ------- apply A: w = W @ (s0*q - s0*colsum(s0*q)), q = x/(sqrt(nsq)+eps), 32-pos tile ----
__global__ __launch_bounds__(256) void apply_A_kernel(const float* __restrict__ x,
                                                      const float* __restrict__ s0,
                                                      const float* __restrict__ Wt,
                                                      float* __restrict__ outw,
                                                      const float* __restrict__ nsq,
                                                      float eps) {
    __shared__ float sx[256][TILE_S + 4];   // +4 pad: breaks 8-way write conflicts
    __shared__ float tsum[8][TILE_S];
    __shared__ float tcol[TILE_S];
    const int tid = threadIdx.x;
    const int b = blockIdx.y;
    const float sca = 1.0f / (sqrtf(nsq[b]) + eps);
    const int sbase = blockIdx.x * TILE_S;
    const float* xb  = x  + (size_t)b * FB;
    const float* s0b = s0 + (size_t)b * FB;
    float*       ob  = outw + (size_t)b * FB;

    const int cq = tid >> 3;         // 0..31
    const int sp = (tid & 7) * 4;    // 0..28
    float4 s0v[8];
#pragma unroll
    for (int r = 0; r < 8; ++r) {
        int c = r * 32 + cq;
        float4 xv = *(const float4*)(xb  + (size_t)c * HWn + sbase + sp);
        float4 sv = *(const float4*)(s0b + (size_t)c * HWn + sbase + sp);
        s0v[r] = sv;
        float4 m;
        m.x = sv.x * (xv.x * sca); m.y = sv.y * (xv.y * sca);
        m.z = sv.z * (xv.z * sca); m.w = sv.w * (xv.w * sca);
        *(float4*)(&sx[c][sp]) = m;
    }
    __syncthreads();
    {
        const int s = tid & 31;
        const int g = tid >> 5;      // 8 groups of 32 channels
        float p = 0.f;
#pragma unroll 8
        for (int c = g * 32; c < g * 32 + 32; ++c) p += sx[c][s];
        tsum[g][s] = p;
    }
    __syncthreads();
    if (tid < 32) {
        float p = 0.f;
#pragma unroll
        for (int g = 0; g < 8; ++g) p += tsum[g][tid];
        tcol[tid] = p;
    }
    __syncthreads();
    {
        float t0 = tcol[sp], t1 = tcol[sp + 1], t2 = tcol[sp + 2], t3 = tcol[sp + 3];
#pragma unroll
        for (int r = 0; r < 8; ++r) {
            int c = r * 32 + cq;
            float4 cur = *(float4*)(&sx[c][sp]);
            cur.x -= s0v[r].x * t0; cur.y -= s0v[r].y * t1;
            cur.z -= s0v[r].z * t2; cur.w -= s0v[r].w * t3;
            *(float4*)(&sx[c][sp]) = cur;
        }
    }
    __syncthreads();
    // GEMM: out[o][s] = sum_c Wt[c][o] * y[c][s], 8x4 per thread
    const int tx = tid >> 3;  // o group (0..31)
    const int ty = tid & 7;   // s group (0..7), 4 floats each
    float acc[8][4] = {};
    const float* wp = Wt + tx * 8;
#pragma unroll 2
    for (int c = 0; c < 256; ++c) {
        float4 w0 = *(const float4*)(wp + c * 256);
        float4 w1 = *(const float4*)(wp + c * 256 + 4);
        float4 y  = *(const float4*)(&sx[c][ty * 4]);
        float wv[8] = {w0.x, w0.y, w0.z, w0.w, w1.x, w1.y, w1.z, w1.w};
        float yv[4] = {y.x, y.y, y.z, y.w};
#pragma unroll
        for (int i = 0; i < 8; ++i)
#pragma unroll
            for (int j = 0; j < 4; ++j)
                acc[i][j] = fmaf(wv[i], yv[j], acc[i][j]);
    }
#pragma unroll
    for (int i = 0; i < 8; ++i) {
        float4 r0 = {acc[i][0], acc[i][1], acc[i][2], acc[i][3]};
        *(float4*)(ob + (size_t)(tx * 8 + i) * HWn + sbase + ty * 4) = r0;
    }
}

// ---------------- expm of 9x9 per batch (fp64); emits final combine coeffs ----------
__global__ __launch_bounds__(128) void expm_kernel(const float* __restrict__ acc,
                                                   float* __restrict__ coordsOut) {
    __shared__ double Am[81], Pm[81], Tm[81];
    __shared__ double ssc;
    __shared__ int sn;
    const int b = blockIdx.x;
    const int t = threadIdx.x;
    const int r = t / 9, c = t % 9;
    if (t < 81) {
        double val = 0.0;
        if (r < 8 && c < 8) {
            if (r <= c) {
                double d = (double)acc[(c * 8 + r) * 8 + b];
                double n = sqrt((double)acc[512 + r * 8 + b]) + ((r == 0) ? 0.0 : (double)EPSK);
                val = TEND * d / n;
            } else if (r == c + 1) {
                val = TEND * sqrt((double)acc[512 + r * 8 + b]);
            }
        }
        if (r == 0 && c == 8) val = TEND;
        Am[t] = val;
    }
    __syncthreads();
    if (t == 0) {
        double mx = 0.0;
        for (int rr = 0; rr < 9; ++rr) {
            double s = 0.0;
            for (int cc = 0; cc < 9; ++cc) s += fabs(Am[rr * 9 + cc]);
            if (s > mx) mx = s;
        }
        int n = 0;
        while (mx > 0.25 && n < 48) { mx *= 0.5; ++n; }
        double sc = 1.0;
        for (int ii = 0; ii < n; ++ii) sc *= 0.5;
        sn = n; ssc = sc;
    }
    __syncthreads();
    if (t < 81) Am[t] *= ssc;
    __syncthreads();
    if (t < 81) Pm[t] = (r == c) ? 1.0 : 0.0;
    __syncthreads();
    for (int i = 20; i >= 1; --i) {
        if (t < 81) {
            double s = 0.0;
            for (int k = 0; k < 9; ++k) s += Am[r * 9 + k] * Pm[k * 9 + c];
            Tm[t] = ((r == c) ? 1.0 : 0.0) + s / (double)i;
        }
        __syncthreads();
        if (t < 81) Pm[t] = Tm[t];
        __syncthreads();
    }
    int n = sn;
    for (int q = 0; q < n; ++q) {
        if (t < 81) {
            double s = 0.0;
            for (int k = 0; k < 9; ++k) s += Pm[r * 9 + k] * Pm[k * 9 + c];
            Tm[t] = s;
        }
        __syncthreads();
        if (t < 81) Pm[t] = Tm[t];
        __syncthreads();
    }
    if (t < 8) {
        double vn = sqrt((double)acc[512 + b]);  // vnorm
        double inv;
        if (t == 0) inv = 1.0 / vn;
        else inv = 1.0 / (sqrt((double)acc[512 + t * 8 + b]) + (double)EPSK);
        coordsOut[b * 8 + t] = (float)(Pm[t * 9 + 8] * vn * inv);
    }
}

// ------ out = coeff_0*v + sum_{j=1..7} coeff_j * U_j ------
__global__ __launch_bounds__(256) void combine_kernel(const float* __restrict__ Qb,
                                                      const float* __restrict__ v,
                                                      const float* __restrict__ coords,
                                                      float* __restrict__ out) {
    int b = blockIdx.y;
    float cf[8];
#pragma unroll
    for (int j = 0; j < 8; ++j) cf[j] = coords[b * 8 + j];
    int i = blockIdx.x * 256 + threadIdx.x;
    float4* ov = (float4*)(out + (size_t)b * FB);
    const float4* vv = (const float4*)(v + (size_t)b * FB);
#pragma unroll
    for (int r = 0; r < 4; ++r) {
        int idx = i + r * 65536;
        float4 q0 = vv[idx];
        float4 a;
        a.x = cf[0] * q0.x; a.y = cf[0] * q0.y;
        a.z = cf[0] * q0.z; a.w = cf[0] * q0.w;
#pragma unroll
        for (int j = 1; j < 8; ++j) {
            const float4* qv = (const float4*)(Qb + (size_t)(j - 1) * NTOT + (size_t)b * FB);
            float4 q = qv[idx];
            a.x = fmaf(cf[j], q.x, a.x); a.y = fmaf(cf[j], q.y, a.y);
            a.z = fmaf(cf[j], q.z, a.z); a.w = fmaf(cf[j], q.w, a.w);
        }
        ov[idx] = a;
    }
}

extern "C" void kernel_launch(void* const* d_in, const int* in_sizes, int n_in,
                              void* d_out, int out_size, void* d_ws, size_t ws_size,
                              hipStream_t stream) {
    const float* s0 = (const float*)d_in[0];
    const float* v  = (const float*)d_in[1];
    const float* W  = (const float*)d_in[2];
    float* out = (float*)d_out;

    // ws layout (floats): [acc 576 | coords 64 | pad -> 1024 | Wt 65536 | U_1..U_7]
    float* ws     = (float*)d_ws;
    float* acc    = ws;
    float* coords = ws + 576;
    float* Wt     = ws + 1024;
    float* Qb     = ws + 1024 + 65536;   // U_j at Qb + (j-1)*NTOT, j=1..7 (224 MiB)
    float* w      = out;                 // reuse d_out as working vector

    init_kernel<<<dim3(1), dim3(256), 0, stream>>>(ws);
    transpose_kernel<<<dim3(256), dim3(256), 0, stream>>>(W, Wt);

    dim3 g(256, 8), blk(256);
    dim3 ga(128, 8);
    norm0_kernel<<<g, blk, 0, stream>>>(v, acc);

    for (int k = 0; k < 8; ++k) {
        if (k > 0) update_kernel<<<g, blk, 0, stream>>>(w, v, Qb, acc, k);
        const float* xk = (k == 0) ? v : (Qb + (size_t)(k - 1) * NTOT);
        float eps = (k == 0) ? 0.0f : EPSK;
        apply_A_kernel<<<ga, blk, 0, stream>>>(xk, s0, Wt, w, acc + 512 + k * 8, eps);
        dots_kernel<<<g, blk, 0, stream>>>(w, v, Qb, acc, k);
    }

    expm_kernel<<<dim3(8), dim3(128), 0, stream>>>(acc, coords);
    combine_kernel<<<g, blk, 0, stream>>>(Qb, v, coords, out);
}

// Round 4
// 1398.605 us; speedup vs baseline: 1.6116x; 1.1506x over previous
//
#include <hip/hip_runtime.h>
#include <math.h>

#define Bn   8
#define Cn   256
#define HWn  4096
#define FB   (Cn * HWn)      // 1048576 floats per batch-field
#define NTOT (Bn * FB)       // 8388608 floats per field (32 MiB)
#define TEND 1.0
#define EPSK 1e-12f
#define TILE_S 32

// acc layout (floats, 8 batches each):
//   dots[k][j] at acc[(k*8+j)*8 + b]   (k,j in 0..7)  -> 512 floats
//   nsq[j]     at acc[512 + j*8 + b]                  -> 64 floats
// coords at acc+576 (64 floats)

// ---------------- zero the small stats region ----------------
__global__ void init_kernel(float* __restrict__ p) {
    for (int i = threadIdx.x; i < 1024; i += 256) p[i] = 0.0f;
}

// ---------------- transpose W (256x256) -> Wt[c][o] ----------------
__global__ void transpose_kernel(const float* __restrict__ W, float* __restrict__ Wt) {
    int o = blockIdx.x, c = threadIdx.x;
    Wt[c * 256 + o] = W[o * 256 + c];
}

// ---------------- nsq[0][b] += sum(v*v) ----------------
__global__ __launch_bounds__(256) void norm0_kernel(const float* __restrict__ v,
                                                    float* __restrict__ acc) {
    int b = blockIdx.y;
    const float4* av = (const float4*)(v + (size_t)b * FB);
    int i = blockIdx.x * 256 + threadIdx.x;
    float p = 0.f;
#pragma unroll
    for (int r = 0; r < 4; ++r) {
        float4 x = av[i + r * 65536];
        p = fmaf(x.x, x.x, p); p = fmaf(x.y, x.y, p);
        p = fmaf(x.z, x.z, p); p = fmaf(x.w, x.w, p);
    }
    for (int off = 32; off > 0; off >>= 1) p += __shfl_down(p, off);
    __shared__ float red[4];
    int lane = threadIdx.x & 63, wid = threadIdx.x >> 6;
    if (lane == 0) red[wid] = p;
    __syncthreads();
    if (threadIdx.x == 0) atomicAdd(&acc[512 + b], red[0] + red[1] + red[2] + red[3]);
}

// -------- dots pass (CGS): d_j = <U_j, w> raw, j=0..NU-1, single read of w --------
// NU = k+1 streams (U_0 = v, U_j = Qb + (j-1)*NTOT). Fully compile-time stream list.
template <int NU>
__global__ __launch_bounds__(256) void dots_kernel(const float* __restrict__ w,
                                                   const float* __restrict__ v,
                                                   const float* __restrict__ Qb,
                                                   float* __restrict__ acc, int k) {
    const int b = blockIdx.y;
    const size_t boff = (size_t)b * FB;
    const float4* wv = (const float4*)(w + boff);
    const float4* uv[NU];
#pragma unroll
    for (int j = 0; j < NU; ++j)
        uv[j] = (const float4*)(((j == 0) ? v : (Qb + (size_t)(j - 1) * NTOT)) + boff);
    int i = blockIdx.x * 256 + threadIdx.x;
    float p[NU];
#pragma unroll
    for (int j = 0; j < NU; ++j) p[j] = 0.f;
#pragma unroll
    for (int r = 0; r < 4; ++r) {
        int idx = i + r * 65536;
        float4 u[NU];
#pragma unroll
        for (int j = 0; j < NU; ++j) u[j] = uv[j][idx];
        float4 x = wv[idx];
#pragma unroll
        for (int j = 0; j < NU; ++j) {
            p[j] = fmaf(u[j].x, x.x, p[j]); p[j] = fmaf(u[j].y, x.y, p[j]);
            p[j] = fmaf(u[j].z, x.z, p[j]); p[j] = fmaf(u[j].w, x.w, p[j]);
        }
    }
    __shared__ float red[4][NU];
    int lane = threadIdx.x & 63, wid = threadIdx.x >> 6;
#pragma unroll
    for (int j = 0; j < NU; ++j) {
        float q = p[j];
        for (int off = 32; off > 0; off >>= 1) q += __shfl_down(q, off);
        if (lane == 0) red[wid][j] = q;
    }
    __syncthreads();
    if (threadIdx.x < NU)
        atomicAdd(&acc[(k * 8 + threadIdx.x) * 8 + b],
                  red[0][threadIdx.x] + red[1][threadIdx.x] +
                  red[2][threadIdx.x] + red[3][threadIdx.x]);
}

// -------- CGS update: U_k = w - sum_{j<K} (d_j/(n_j+e)^2) U_j;  nsq[K] += ||U_K||^2 ----
// K = k (number of previous streams). Writes U_K at Qb+(K-1)*NTOT.
template <int K>
__global__ __launch_bounds__(256) void update_kernel(const float* __restrict__ w,
                                                     const float* __restrict__ v,
                                                     float* __restrict__ Qb,
                                                     float* __restrict__ acc) {
    const int b = blockIdx.y;
    const size_t boff = (size_t)b * FB;
    float cj[K];
#pragma unroll
    for (int j = 0; j < K; ++j) {
        float d  = acc[((K - 1) * 8 + j) * 8 + b];
        float n2 = acc[512 + j * 8 + b];
        float nn = sqrtf(n2) + ((j == 0) ? 0.f : EPSK);
        cj[j] = d / (nn * nn);
    }
    const float4* wv = (const float4*)(w + boff);
    const float4* uv[K];
#pragma unroll
    for (int j = 0; j < K; ++j)
        uv[j] = (const float4*)(((j == 0) ? v : (Qb + (size_t)(j - 1) * NTOT)) + boff);
    float4* Uk = (float4*)(Qb + (size_t)(K - 1) * NTOT + boff);
    int i = blockIdx.x * 256 + threadIdx.x;
    float p = 0.f;
#pragma unroll
    for (int r = 0; r < 4; ++r) {
        int idx = i + r * 65536;
        float4 u[K];
#pragma unroll
        for (int j = 0; j < K; ++j) u[j] = uv[j][idx];
        float4 x = wv[idx];
#pragma unroll
        for (int j = 0; j < K; ++j) {
            x.x = fmaf(-cj[j], u[j].x, x.x); x.y = fmaf(-cj[j], u[j].y, x.y);
            x.z = fmaf(-cj[j], u[j].z, x.z); x.w = fmaf(-cj[j], u[j].w, x.w);
        }
        Uk[idx] = x;
        p = fmaf(x.x, x.x, p); p = fmaf(x.y, x.y, p);
        p = fmaf(x.z, x.z, p); p = fmaf(x.w, x.w, p);
    }
    for (int off = 32; off > 0; off >>= 1) p += __shfl_down(p, off);
    __shared__ float red[4];
    int lane = threadIdx.x & 63, wid = threadIdx.x >> 6;
    if (lane == 0) red[wid] = p;
    __syncthreads();
    if (threadIdx.x == 0)
        atomicAdd(&acc[512 + K * 8 + b], red[0] + red[1] + red[2] + red[3]);
}

// ------- apply A: w = W @ (s0*q - s0*colsum(s0*q)), q = x/(sqrt(nsq)+eps), 32-pos tile ----
__global__ __launch_bounds__(256) void apply_A_kernel(const float* __restrict__ x,
                                                      const float* __restrict__ s0,
                                                      const float* __restrict__ Wt,
                                                      float* __restrict__ outw,
                                                      const float* __restrict__ nsq,
                                                      float eps) {
    __shared__ float sx[256][TILE_S + 4];   // +4 pad
    __shared__ float tsum[8][TILE_S];
    __shared__ float tcol[TILE_S];
    const int tid = threadIdx.x;
    const int b = blockIdx.y;
    const float sca = 1.0f / (sqrtf(nsq[b]) + eps);
    const int sbase = blockIdx.x * TILE_S;
    const float* xb  = x  + (size_t)b * FB;
    const float* s0b = s0 + (size_t)b * FB;
    float*       ob  = outw + (size_t)b * FB;

    const int cq = tid >> 3;         // 0..31
    const int sp = (tid & 7) * 4;    // 0..28
    float4 s0v[8];
#pragma unroll
    for (int r = 0; r < 8; ++r) {
        int c = r * 32 + cq;
        float4 xv = *(const float4*)(xb  + (size_t)c * HWn + sbase + sp);
        float4 sv = *(const float4*)(s0b + (size_t)c * HWn + sbase + sp);
        s0v[r] = sv;
        float4 m;
        m.x = sv.x * (xv.x * sca); m.y = sv.y * (xv.y * sca);
        m.z = sv.z * (xv.z * sca); m.w = sv.w * (xv.w * sca);
        *(float4*)(&sx[c][sp]) = m;
    }
    __syncthreads();
    {
        const int s = tid & 31;
        const int g = tid >> 5;
        float p = 0.f;
#pragma unroll 8
        for (int c = g * 32; c < g * 32 + 32; ++c) p += sx[c][s];
        tsum[g][s] = p;
    }
    __syncthreads();
    if (tid < 32) {
        float p = 0.f;
#pragma unroll
        for (int g = 0; g < 8; ++g) p += tsum[g][tid];
        tcol[tid] = p;
    }
    __syncthreads();
    {
        float t0 = tcol[sp], t1 = tcol[sp + 1], t2 = tcol[sp + 2], t3 = tcol[sp + 3];
#pragma unroll
        for (int r = 0; r < 8; ++r) {
            int c = r * 32 + cq;
            float4 cur = *(float4*)(&sx[c][sp]);
            cur.x -= s0v[r].x * t0; cur.y -= s0v[r].y * t1;
            cur.z -= s0v[r].z * t2; cur.w -= s0v[r].w * t3;
            *(float4*)(&sx[c][sp]) = cur;
        }
    }
    __syncthreads();
    const int tx = tid >> 3;  // o group (0..31)
    const int ty = tid & 7;   // s group (0..7)
    float acc[8][4] = {};
    const float* wp = Wt + tx * 8;
#pragma unroll 2
    for (int c = 0; c < 256; ++c) {
        float4 w0 = *(const float4*)(wp + c * 256);
        float4 w1 = *(const float4*)(wp + c * 256 + 4);
        float4 y  = *(const float4*)(&sx[c][ty * 4]);
        float wv[8] = {w0.x, w0.y, w0.z, w0.w, w1.x, w1.y, w1.z, w1.w};
        float yv[4] = {y.x, y.y, y.z, y.w};
#pragma unroll
        for (int i = 0; i < 8; ++i)
#pragma unroll
            for (int j = 0; j < 4; ++j)
                acc[i][j] = fmaf(wv[i], yv[j], acc[i][j]);
    }
#pragma unroll
    for (int i = 0; i < 8; ++i) {
        float4 r0 = {acc[i][0], acc[i][1], acc[i][2], acc[i][3]};
        *(float4*)(ob + (size_t)(tx * 8 + i) * HWn + sbase + ty * 4) = r0;
    }
}

// ---------------- expm of 9x9 per batch (fp64); emits final combine coeffs ----------
__global__ __launch_bounds__(128) void expm_kernel(const float* __restrict__ acc,
                                                   float* __restrict__ coordsOut) {
    __shared__ double Am[81], Pm[81], Tm[81];
    __shared__ double ssc;
    __shared__ int sn;
    const int b = blockIdx.x;
    const int t = threadIdx.x;
    const int r = t / 9, c = t % 9;
    if (t < 81) {
        double val = 0.0;
        if (r < 8 && c < 8) {
            if (r <= c) {
                double d = (double)acc[(c * 8 + r) * 8 + b];
                double n = sqrt((double)acc[512 + r * 8 + b]) + ((r == 0) ? 0.0 : (double)EPSK);
                val = TEND * d / n;
            } else if (r == c + 1) {
                val = TEND * sqrt((double)acc[512 + r * 8 + b]);
            }
        }
        if (r == 0 && c == 8) val = TEND;
        Am[t] = val;
    }
    __syncthreads();
    if (t == 0) {
        double mx = 0.0;
        for (int rr = 0; rr < 9; ++rr) {
            double s = 0.0;
            for (int cc = 0; cc < 9; ++cc) s += fabs(Am[rr * 9 + cc]);
            if (s > mx) mx = s;
        }
        int n = 0;
        while (mx > 0.25 && n < 48) { mx *= 0.5; ++n; }
        double sc = 1.0;
        for (int ii = 0; ii < n; ++ii) sc *= 0.5;
        sn = n; ssc = sc;
    }
    __syncthreads();
    if (t < 81) Am[t] *= ssc;
    __syncthreads();
    if (t < 81) Pm[t] = (r == c) ? 1.0 : 0.0;
    __syncthreads();
    for (int i = 20; i >= 1; --i) {
        if (t < 81) {
            double s = 0.0;
            for (int k = 0; k < 9; ++k) s += Am[r * 9 + k] * Pm[k * 9 + c];
            Tm[t] = ((r == c) ? 1.0 : 0.0) + s / (double)i;
        }
        __syncthreads();
        if (t < 81) Pm[t] = Tm[t];
        __syncthreads();
    }
    int n = sn;
    for (int q = 0; q < n; ++q) {
        if (t < 81) {
            double s = 0.0;
            for (int k = 0; k < 9; ++k) s += Pm[r * 9 + k] * Pm[k * 9 + c];
            Tm[t] = s;
        }
        __syncthreads();
        if (t < 81) Pm[t] = Tm[t];
        __syncthreads();
    }
    if (t < 8) {
        double vn = sqrt((double)acc[512 + b]);
        double inv;
        if (t == 0) inv = 1.0 / vn;
        else inv = 1.0 / (sqrt((double)acc[512 + t * 8 + b]) + (double)EPSK);
        coordsOut[b * 8 + t] = (float)(Pm[t * 9 + 8] * vn * inv);
    }
}

// ------ out = coeff_0*v + sum_{j=1..7} coeff_j * U_j ------
__global__ __launch_bounds__(256) void combine_kernel(const float* __restrict__ Qb,
                                                      const float* __restrict__ v,
                                                      const float* __restrict__ coords,
                                                      float* __restrict__ out) {
    int b = blockIdx.y;
    const size_t boff = (size_t)b * FB;
    float cf[8];
#pragma unroll
    for (int j = 0; j < 8; ++j) cf[j] = coords[b * 8 + j];
    const float4* uv[8];
    uv[0] = (const float4*)(v + boff);
#pragma unroll
    for (int j = 1; j < 8; ++j)
        uv[j] = (const float4*)(Qb + (size_t)(j - 1) * NTOT + boff);
    int i = blockIdx.x * 256 + threadIdx.x;
    float4* ov = (float4*)(out + boff);
#pragma unroll
    for (int r = 0; r < 4; ++r) {
        int idx = i + r * 65536;
        float4 u[8];
#pragma unroll
        for (int j = 0; j < 8; ++j) u[j] = uv[j][idx];
        float4 a = {0.f, 0.f, 0.f, 0.f};
#pragma unroll
        for (int j = 0; j < 8; ++j) {
            a.x = fmaf(cf[j], u[j].x, a.x); a.y = fmaf(cf[j], u[j].y, a.y);
            a.z = fmaf(cf[j], u[j].z, a.z); a.w = fmaf(cf[j], u[j].w, a.w);
        }
        ov[idx] = a;
    }
}

extern "C" void kernel_launch(void* const* d_in, const int* in_sizes, int n_in,
                              void* d_out, int out_size, void* d_ws, size_t ws_size,
                              hipStream_t stream) {
    const float* s0 = (const float*)d_in[0];
    const float* v  = (const float*)d_in[1];
    const float* W  = (const float*)d_in[2];
    float* out = (float*)d_out;

    float* ws     = (float*)d_ws;
    float* acc    = ws;
    float* coords = ws + 576;
    float* Wt     = ws + 1024;
    float* Qb     = ws + 1024 + 65536;   // U_j at Qb + (j-1)*NTOT, j=1..7 (224 MiB)
    float* w      = out;                 // reuse d_out as working vector

    init_kernel<<<dim3(1), dim3(256), 0, stream>>>(ws);
    transpose_kernel<<<dim3(256), dim3(256), 0, stream>>>(W, Wt);

    dim3 g(256, 8), blk(256);
    dim3 ga(128, 8);
    norm0_kernel<<<g, blk, 0, stream>>>(v, acc);

    for (int k = 0; k < 8; ++k) {
        switch (k) {
            case 1: update_kernel<1><<<g, blk, 0, stream>>>(w, v, Qb, acc); break;
            case 2: update_kernel<2><<<g, blk, 0, stream>>>(w, v, Qb, acc); break;
            case 3: update_kernel<3><<<g, blk, 0, stream>>>(w, v, Qb, acc); break;
            case 4: update_kernel<4><<<g, blk, 0, stream>>>(w, v, Qb, acc); break;
            case 5: update_kernel<5><<<g, blk, 0, stream>>>(w, v, Qb, acc); break;
            case 6: update_kernel<6><<<g, blk, 0, stream>>>(w, v, Qb, acc); break;
            case 7: update_kernel<7><<<g, blk, 0, stream>>>(w, v, Qb, acc); break;
            default: break;
        }
        const float* xk = (k == 0) ? v : (Qb + (size_t)(k - 1) * NTOT);
        float eps = (k == 0) ? 0.0f : EPSK;
        apply_A_kernel<<<ga, blk, 0, stream>>>(xk, s0, Wt, w, acc + 512 + k * 8, eps);
        switch (k) {
            case 0: dots_kernel<1><<<g, blk, 0, stream>>>(w, v, Qb, acc, k); break;
            case 1: dots_kernel<2><<<g, blk, 0, stream>>>(w, v, Qb, acc, k); break;
            case 2: dots_kernel<3><<<g, blk, 0, stream>>>(w, v, Qb, acc, k); break;
            case 3: dots_kernel<4><<<g, blk, 0, stream>>>(w, v, Qb, acc, k); break;
            case 4: dots_kernel<5><<<g, blk, 0, stream>>>(w, v, Qb, acc, k); break;
            case 5: dots_kernel<6><<<g, blk, 0, stream>>>(w, v, Qb, acc, k); break;
            case 6: dots_kernel<7><<<g, blk, 0, stream>>>(w, v, Qb, acc, k); break;
            case 7: dots_kernel<8><<<g, blk, 0, stream>>>(w, v, Qb, acc, k); break;
        }
    }

    expm_kernel<<<dim3(8), dim3(128), 0, stream>>>(acc, coords);
    combine_kernel<<<g, blk, 0, stream>>>(Qb, v, coords, out);
}

// Round 6
// 1359.831 us; speedup vs baseline: 1.6575x; 1.0285x over previous
//
#include <hip/hip_runtime.h>
#include <math.h>

#define Bn   8
#define Cn   256
#define HWn  4096
#define FB   (Cn * HWn)      // 1048576 floats per batch-field
#define NTOT (Bn * FB)       // 8388608 floats per field (32 MiB)
#define TEND 1.0
#define EPSK 1e-12f
#define TILE_S 32

// acc layout (floats, 8 batches each):
//   D[k][j] = <U_j, A(U_k)>  at acc[(k*8+j)*8 + b]   -> 512 floats
//   Nsq[j]  = <U_j, U_j>     at acc[512 + j*8 + b]   -> 64 floats
// coords at acc+576 (64 floats)
// Scale bookkeeping (all in expm kernel, fp64):
//   m_0 = sqrt(Nsq[0]);  m_j = sqrt(Nsq[j]) + EPS*m_{j-1}
//   H[j][k] = D[k][j]/(m_j m_k);  H[k+1][k] = sqrt(Nsq[k+1])/m_k
//   combine coeff_j = expm[j][8] * m_0 / m_j

// ---------------- zero the small stats region ----------------
__global__ void init_kernel(float* __restrict__ p) {
    for (int i = threadIdx.x; i < 1024; i += 256) p[i] = 0.0f;
}

// ---------------- transpose W (256x256) -> Wt[c][o] ----------------
__global__ void transpose_kernel(const float* __restrict__ W, float* __restrict__ Wt) {
    int o = blockIdx.x, c = threadIdx.x;
    Wt[c * 256 + o] = W[o * 256 + c];
}

// ================= fused Krylov step K =================
// Phase 1: U_K = win - sum_{j<K} c_j U_j (elementwise, c_j from prev step's stats);
//          write U_K, accumulate Nsq[K], stage s0*U_K in LDS.  (K=0: U_0 = v = win)
// Phase 2: per-position colsum t, y = s0*U_K - s0*t  (replicator)
// Phase 3: w' = Wt^T y (per-tile GEMM, 8x4 per thread)
// Phase 4: store w', accumulate D[K][j] = <U_j, w'> for j=0..K.
template <int K>
__global__ __launch_bounds__(256, 4) void fused_step_kernel(
        const float* win,                      // prev A-output (aliases wout), or v for K=0
        const float* __restrict__ v,
        float* __restrict__ Qb,                // U_j at Qb + (j-1)*NTOT, j>=1
        const float* __restrict__ s0,
        const float* __restrict__ Wt,
        float* wout,                           // A(U_K) output (aliases win)
        float* __restrict__ acc) {
    constexpr int KP = (K > 0) ? K : 1;        // padded size so K=0 compiles
    __shared__ float sx[256][TILE_S + 4];      // 36 KB
    __shared__ float tsum[8][TILE_S];
    __shared__ float tcol[TILE_S];
    __shared__ float redn[4];
    __shared__ float redd[4][K + 1];

    const int tid = threadIdx.x;
    const int b = blockIdx.y;
    const int sbase = blockIdx.x * TILE_S;
    const size_t boff = (size_t)b * FB;

    // ---- CGS coefficients (uniform per block) ----
    float cj[KP];
    if constexpr (K > 0) {
        float m[KP];
        m[0] = sqrtf(acc[512 + b]);
#pragma unroll
        for (int j = 1; j < K; ++j) m[j] = sqrtf(acc[512 + j * 8 + b]) + EPSK * m[j - 1];
#pragma unroll
        for (int j = 0; j < K; ++j)
            cj[j] = acc[((K - 1) * 8 + j) * 8 + b] / (m[j] * m[j]);
    } else {
        cj[0] = 0.f;
    }

    // ---- Phase 1: staging + update + Nsq ----
    const int cq = tid >> 3;         // 0..31
    const int sp = (tid & 7) * 4;    // 0..28
    float4 s0v[8];
    float np = 0.f;
#pragma unroll
    for (int r = 0; r < 8; ++r) {
        const int c = r * 32 + cq;
        const size_t off = (size_t)c * HWn + sbase + sp;
        float4 x = *(const float4*)(win + boff + off);
        float4 sv = *(const float4*)(s0 + boff + off);
        if constexpr (K > 0) {
            float4 u[KP];
#pragma unroll
            for (int j = 0; j < K; ++j) {
                const float* Us = (j == 0) ? v : (Qb + (size_t)(j - 1) * NTOT);
                u[j] = *(const float4*)(Us + boff + off);
            }
#pragma unroll
            for (int j = 0; j < K; ++j) {
                x.x = fmaf(-cj[j], u[j].x, x.x); x.y = fmaf(-cj[j], u[j].y, x.y);
                x.z = fmaf(-cj[j], u[j].z, x.z); x.w = fmaf(-cj[j], u[j].w, x.w);
            }
            *(float4*)(Qb + (size_t)(K - 1) * NTOT + boff + off) = x;
        }
        np = fmaf(x.x, x.x, np); np = fmaf(x.y, x.y, np);
        np = fmaf(x.z, x.z, np); np = fmaf(x.w, x.w, np);
        s0v[r] = sv;
        float4 mm = {sv.x * x.x, sv.y * x.y, sv.z * x.z, sv.w * x.w};
        *(float4*)(&sx[c][sp]) = mm;
    }
    for (int o2 = 32; o2 > 0; o2 >>= 1) np += __shfl_down(np, o2);
    if ((tid & 63) == 0) redn[tid >> 6] = np;
    __syncthreads();   // covers sx writes + redn
    if (tid == 0) atomicAdd(&acc[512 + K * 8 + b], redn[0] + redn[1] + redn[2] + redn[3]);

    // ---- Phase 2: replicator ----
    {
        const int s = tid & 31;
        const int g = tid >> 5;
        float p = 0.f;
#pragma unroll 8
        for (int c = g * 32; c < g * 32 + 32; ++c) p += sx[c][s];
        tsum[g][s] = p;
    }
    __syncthreads();
    if (tid < 32) {
        float p = 0.f;
#pragma unroll
        for (int g = 0; g < 8; ++g) p += tsum[g][tid];
        tcol[tid] = p;
    }
    __syncthreads();
    {
        float t0 = tcol[sp], t1 = tcol[sp + 1], t2 = tcol[sp + 2], t3 = tcol[sp + 3];
#pragma unroll
        for (int r = 0; r < 8; ++r) {
            int c = r * 32 + cq;
            float4 cur = *(float4*)(&sx[c][sp]);
            cur.x -= s0v[r].x * t0; cur.y -= s0v[r].y * t1;
            cur.z -= s0v[r].z * t2; cur.w -= s0v[r].w * t3;
            *(float4*)(&sx[c][sp]) = cur;
        }
    }
    __syncthreads();

    // ---- Phase 3: GEMM w'[o][s] = sum_c Wt[c][o] * y[c][s] ----
    const int tx = tid >> 3;  // o group (0..31)
    const int ty = tid & 7;   // s group (0..7)
    float av[8][4] = {};
    const float* wp = Wt + tx * 8;
#pragma unroll 2
    for (int c = 0; c < 256; ++c) {
        float4 w0 = *(const float4*)(wp + c * 256);
        float4 w1 = *(const float4*)(wp + c * 256 + 4);
        float4 y  = *(const float4*)(&sx[c][ty * 4]);
        float wv[8] = {w0.x, w0.y, w0.z, w0.w, w1.x, w1.y, w1.z, w1.w};
        float yv[4] = {y.x, y.y, y.z, y.w};
#pragma unroll
        for (int i = 0; i < 8; ++i)
#pragma unroll
            for (int j = 0; j < 4; ++j)
                av[i][j] = fmaf(wv[i], yv[j], av[i][j]);
    }

    // ---- Phase 4: store w' + dots D[K][j] = <U_j, w'> ----
    const float* Uj[K + 1];
    Uj[0] = v + boff;
#pragma unroll
    for (int j = 1; j <= K; ++j) Uj[j] = Qb + (size_t)(j - 1) * NTOT + boff;
    float pd[K + 1];
#pragma unroll
    for (int j = 0; j <= K; ++j) pd[j] = 0.f;
#pragma unroll
    for (int i = 0; i < 8; ++i) {
        const size_t off = (size_t)(tx * 8 + i) * HWn + sbase + ty * 4;
        float4 r0 = {av[i][0], av[i][1], av[i][2], av[i][3]};
        *(float4*)(wout + boff + off) = r0;
#pragma unroll
        for (int j = 0; j <= K; ++j) {
            float4 uu = *(const float4*)(Uj[j] + off);
            pd[j] = fmaf(uu.x, r0.x, pd[j]); pd[j] = fmaf(uu.y, r0.y, pd[j]);
            pd[j] = fmaf(uu.z, r0.z, pd[j]); pd[j] = fmaf(uu.w, r0.w, pd[j]);
        }
    }
    int lane = tid & 63, wid = tid >> 6;
#pragma unroll
    for (int j = 0; j <= K; ++j) {
        float q = pd[j];
        for (int o2 = 32; o2 > 0; o2 >>= 1) q += __shfl_down(q, o2);
        if (lane == 0) redd[wid][j] = q;
    }
    __syncthreads();
    if (tid <= K)
        atomicAdd(&acc[(K * 8 + tid) * 8 + b],
                  redd[0][tid] + redd[1][tid] + redd[2][tid] + redd[3][tid]);
}

// ---------------- expm of 9x9 per batch (fp64); emits final combine coeffs ----------
__global__ __launch_bounds__(128) void expm_kernel(const float* __restrict__ acc,
                                                   float* __restrict__ coordsOut) {
    __shared__ double Am[81], Pm[81], Tm[81];
    __shared__ double ssc;
    __shared__ int sn;
    const int b = blockIdx.x;
    const int t = threadIdx.x;
    const int r = t / 9, c = t % 9;
    double m[8];
    m[0] = sqrt((double)acc[512 + b]);
    for (int j = 1; j < 8; ++j) m[j] = sqrt((double)acc[512 + j * 8 + b]) + 1e-12 * m[j - 1];
    if (t < 81) {
        double val = 0.0;
        if (r < 8 && c < 8) {
            if (r <= c) {
                val = TEND * (double)acc[(c * 8 + r) * 8 + b] / (m[r] * m[c]);
            } else if (r == c + 1) {
                val = TEND * sqrt((double)acc[512 + r * 8 + b]) / m[c];
            }
        }
        if (r == 0 && c == 8) val = TEND;
        Am[t] = val;
    }
    __syncthreads();
    if (t == 0) {
        double mx = 0.0;
        for (int rr = 0; rr < 9; ++rr) {
            double s = 0.0;
            for (int cc = 0; cc < 9; ++cc) s += fabs(Am[rr * 9 + cc]);
            if (s > mx) mx = s;
        }
        int n = 0;
        while (mx > 0.25 && n < 48) { mx *= 0.5; ++n; }
        double sc = 1.0;
        for (int ii = 0; ii < n; ++ii) sc *= 0.5;
        sn = n; ssc = sc;
    }
    __syncthreads();
    if (t < 81) Am[t] *= ssc;
    __syncthreads();
    if (t < 81) Pm[t] = (r == c) ? 1.0 : 0.0;
    __syncthreads();
    for (int i = 20; i >= 1; --i) {
        if (t < 81) {
            double s = 0.0;
            for (int k = 0; k < 9; ++k) s += Am[r * 9 + k] * Pm[k * 9 + c];
            Tm[t] = ((r == c) ? 1.0 : 0.0) + s / (double)i;
        }
        __syncthreads();
        if (t < 81) Pm[t] = Tm[t];
        __syncthreads();
    }
    int n = sn;
    for (int q = 0; q < n; ++q) {
        if (t < 81) {
            double s = 0.0;
            for (int k = 0; k < 9; ++k) s += Pm[r * 9 + k] * Pm[k * 9 + c];
            Tm[t] = s;
        }
        __syncthreads();
        if (t < 81) Pm[t] = Tm[t];
        __syncthreads();
    }
    if (t < 8) {
        coordsOut[b * 8 + t] = (float)(Pm[t * 9 + 8] * m[0] / m[t]);
    }
}

// ------ out = coeff_0*v + sum_{j=1..7} coeff_j * U_j ------
__global__ __launch_bounds__(256) void combine_kernel(const float* __restrict__ Qb,
                                                      const float* __restrict__ v,
                                                      const float* __restrict__ coords,
                                                      float* __restrict__ out) {
    int b = blockIdx.y;
    const size_t boff = (size_t)b * FB;
    float cf[8];
#pragma unroll
    for (int j = 0; j < 8; ++j) cf[j] = coords[b * 8 + j];
    const float4* uv[8];
    uv[0] = (const float4*)(v + boff);
#pragma unroll
    for (int j = 1; j < 8; ++j)
        uv[j] = (const float4*)(Qb + (size_t)(j - 1) * NTOT + boff);
    int i = blockIdx.x * 256 + threadIdx.x;
    float4* ov = (float4*)(out + boff);
#pragma unroll
    for (int r = 0; r < 4; ++r) {
        int idx = i + r * 65536;
        float4 u[8];
#pragma unroll
        for (int j = 0; j < 8; ++j) u[j] = uv[j][idx];
        float4 a = {0.f, 0.f, 0.f, 0.f};
#pragma unroll
        for (int j = 0; j < 8; ++j) {
            a.x = fmaf(cf[j], u[j].x, a.x); a.y = fmaf(cf[j], u[j].y, a.y);
            a.z = fmaf(cf[j], u[j].z, a.z); a.w = fmaf(cf[j], u[j].w, a.w);
        }
        ov[idx] = a;
    }
}

extern "C" void kernel_launch(void* const* d_in, const int* in_sizes, int n_in,
                              void* d_out, int out_size, void* d_ws, size_t ws_size,
                              hipStream_t stream) {
    const float* s0 = (const float*)d_in[0];
    const float* v  = (const float*)d_in[1];
    const float* W  = (const float*)d_in[2];
    float* out = (float*)d_out;

    float* ws     = (float*)d_ws;
    float* acc    = ws;
    float* coords = ws + 576;
    float* Wt     = ws + 1024;
    float* Qb     = ws + 1024 + 65536;   // U_j at Qb + (j-1)*NTOT, j=1..7 (224 MiB)
    float* w      = out;                 // A-output buffer (reused in place)

    init_kernel<<<dim3(1), dim3(256), 0, stream>>>(ws);
    transpose_kernel<<<dim3(256), dim3(256), 0, stream>>>(W, Wt);

    dim3 gf(128, 8), blk(256);
    fused_step_kernel<0><<<gf, blk, 0, stream>>>(v, v, Qb, s0, Wt, w, acc);
    fused_step_kernel<1><<<gf, blk, 0, stream>>>(w, v, Qb, s0, Wt, w, acc);
    fused_step_kernel<2><<<gf, blk, 0, stream>>>(w, v, Qb, s0, Wt, w, acc);
    fused_step_kernel<3><<<gf, blk, 0, stream>>>(w, v, Qb, s0, Wt, w, acc);
    fused_step_kernel<4><<<gf, blk, 0, stream>>>(w, v, Qb, s0, Wt, w, acc);
    fused_step_kernel<5><<<gf, blk, 0, stream>>>(w, v, Qb, s0, Wt, w, acc);
    fused_step_kernel<6><<<gf, blk, 0, stream>>>(w, v, Qb, s0, Wt, w, acc);
    fused_step_kernel<7><<<gf, blk, 0, stream>>>(w, v, Qb, s0, Wt, w, acc);

    expm_kernel<<<dim3(8), dim3(128), 0, stream>>>(acc, coords);
    dim3 g(256, 8);
    combine_kernel<<<g, blk, 0, stream>>>(Qb, v, coords, out);
}

// Round 7
// 983.276 us; speedup vs baseline: 2.2923x; 1.3830x over previous
//
#include <hip/hip_runtime.h>
#include <math.h>

#define Bn   8
#define Cn   256
#define HWn  4096
#define FB   (Cn * HWn)      // 1048576 elems per batch-field
#define NTOT (Bn * FB)       // 8388608 elems per field
#define TEND 1.0
#define EPSK 1e-12f
#define NT   64              // apply N-tile (positions)
#define RS   56              // Pb LDS row stride (bf16) — 112B: 2-way bank alias only

typedef float f32x4 __attribute__((ext_vector_type(4)));
typedef short bf16x8 __attribute__((ext_vector_type(8)));

__device__ inline float b2f(unsigned int u) {
    return __uint_as_float(u << 16);
}
__device__ inline unsigned short f2b(float f) {  // RNE
    unsigned u = __float_as_uint(f);
    unsigned r = u + 0x7FFFu + ((u >> 16) & 1u);
    return (unsigned short)(r >> 16);
}
__device__ inline void unp8(uint4 u, float* f) {
    f[0] = b2f(u.x & 0xFFFFu); f[1] = b2f(u.x >> 16);
    f[2] = b2f(u.y & 0xFFFFu); f[3] = b2f(u.y >> 16);
    f[4] = b2f(u.z & 0xFFFFu); f[5] = b2f(u.z >> 16);
    f[6] = b2f(u.w & 0xFFFFu); f[7] = b2f(u.w >> 16);
}

// acc layout (floats, 8 batches each):
//   D[k][j] at acc[(k*8+j)*8 + b];  Nsq[j] at acc[512 + j*8 + b];  coords at acc+576

__global__ void init_kernel(float* __restrict__ p) {
    for (int i = threadIdx.x; i < 1024; i += 256) p[i] = 0.0f;
}

// ---- split W into bf16 hi/lo in MFMA-A staged layout ----
// layout: Whs[((kc*16+mt)*64+lane)*8+j] = bf16 of W[mt*16+(lane&15)][kc*32+(lane>>4)*8+j]
__global__ void wsplit_kernel(const float* __restrict__ W,
                              unsigned short* __restrict__ Whs,
                              unsigned short* __restrict__ Wls) {
    int kc = blockIdx.x, mt = blockIdx.y, l = threadIdx.x;
    int m = mt * 16 + (l & 15);
    int k0 = kc * 32 + (l >> 4) * 8;
#pragma unroll
    for (int j = 0; j < 8; ++j) {
        float wv = W[m * 256 + k0 + j];
        unsigned short h = f2b(wv);
        unsigned short lo = f2b(wv - b2f(h));
        int idx = ((kc * 16 + mt) * 64 + l) * 8 + j;
        Whs[idx] = h; Wls[idx] = lo;
    }
}

// ---- Nsq[0][b] = ||v||^2 ----
__global__ __launch_bounds__(256) void norm0_kernel(const float* __restrict__ v,
                                                    float* __restrict__ acc) {
    int b = blockIdx.y;
    const float4* av = (const float4*)(v + (size_t)b * FB);
    int i = blockIdx.x * 256 + threadIdx.x;
    float p = 0.f;
#pragma unroll
    for (int r = 0; r < 4; ++r) {
        float4 x = av[i + r * 65536];
        p = fmaf(x.x, x.x, p); p = fmaf(x.y, x.y, p);
        p = fmaf(x.z, x.z, p); p = fmaf(x.w, x.w, p);
    }
    for (int off = 32; off > 0; off >>= 1) p += __shfl_down(p, off);
    __shared__ float red[4];
    int lane = threadIdx.x & 63, wid = threadIdx.x >> 6;
    if (lane == 0) red[wid] = p;
    __syncthreads();
    if (threadIdx.x == 0) atomicAdd(&acc[512 + b], red[0] + red[1] + red[2] + red[3]);
}

// ============ MFMA apply: w' = W@(s0*x) - Z.*t,  t = colsum(s0*x) ============
// MODE 0: x bf16 (Qb field); MODE 1: x fp32 (v); MODE 2: Z-mode (P = s0, out = W@s0)
template <int MODE>
__global__ __launch_bounds__(256, 3) void apply_mfma(
        const unsigned short* __restrict__ xb, const float* __restrict__ xf,
        const float* __restrict__ s0,
        const unsigned short* __restrict__ Whs, const unsigned short* __restrict__ Wls,
        const float* __restrict__ Zb, float* __restrict__ wout) {
    __shared__ short Ah[8192], Al[8192];        // 16 KB each
    __shared__ short Ph[NT * RS], Pl[NT * RS];  // 7 KB each
    __shared__ float tred[16 * 64];
    __shared__ float ts[64];
    const int tid = threadIdx.x;
    const int b = blockIdx.y;
    const int sbase = blockIdx.x * NT;
    const size_t boff = (size_t)b * FB;
    const int lane = tid & 63, wv = tid >> 6;
    const int mbase = wv * 64;

    f32x4 acc[4][4];
#pragma unroll
    for (int i = 0; i < 4; ++i)
#pragma unroll
        for (int j = 0; j < 4; ++j) acc[i][j] = (f32x4){0.f, 0.f, 0.f, 0.f};

    const int cg = tid >> 4;         // 0..15
    const int pos = (tid & 15) * 4;  // 0..60
    float tp[4] = {0.f, 0.f, 0.f, 0.f};

    for (int kc = 0; kc < 8; ++kc) {
        __syncthreads();  // protect LDS from previous chunk's reads
        {   // stage A chunk (global, L2-hot)
            const uint4* srcH = (const uint4*)(Whs + kc * 8192);
            const uint4* srcL = (const uint4*)(Wls + kc * 8192);
            uint4* dH = (uint4*)Ah; uint4* dL = (uint4*)Al;
#pragma unroll
            for (int i = 0; i < 4; ++i) {
                dH[tid + i * 256] = srcH[tid + i * 256];
                dL[tid + i * 256] = srcL[tid + i * 256];
            }
        }
        // stage B chunk: P = s0*x, hi/lo split, accumulate t partials
#pragma unroll
        for (int ci = 0; ci < 2; ++ci) {
            int cl = ci * 16 + cg;          // 0..31
            int c = kc * 32 + cl;
            size_t off = boff + (size_t)c * HWn + sbase + pos;
            float4 sv = *(const float4*)(s0 + off);
            float p[4];
            if (MODE == 2) { p[0] = sv.x; p[1] = sv.y; p[2] = sv.z; p[3] = sv.w; }
            else if (MODE == 1) {
                float4 xv = *(const float4*)(xf + off);
                p[0] = xv.x * sv.x; p[1] = xv.y * sv.y;
                p[2] = xv.z * sv.z; p[3] = xv.w * sv.w;
            } else {
                ushort4 xv = *(const ushort4*)(xb + off);
                p[0] = b2f(xv.x) * sv.x; p[1] = b2f(xv.y) * sv.y;
                p[2] = b2f(xv.z) * sv.z; p[3] = b2f(xv.w) * sv.w;
            }
#pragma unroll
            for (int i = 0; i < 4; ++i) {
                if (MODE != 2) tp[i] += p[i];
                unsigned short h = f2b(p[i]);
                unsigned short l = f2b(p[i] - b2f(h));
                Ph[(pos + i) * RS + cl] = (short)h;
                Pl[(pos + i) * RS + cl] = (short)l;
            }
        }
        __syncthreads();
        // MFMA: D[m][n] += A[m][k] B[k][n], split products hh + hl + lh
        bf16x8 ah[4], al[4], bh[4], bl[4];
#pragma unroll
        for (int rt = 0; rt < 4; ++rt) {
            int mt = (mbase >> 4) + rt;
            ah[rt] = *(bf16x8*)(Ah + (mt * 64 + lane) * 8);
            al[rt] = *(bf16x8*)(Al + (mt * 64 + lane) * 8);
        }
#pragma unroll
        for (int ct = 0; ct < 4; ++ct) {
            int n = ct * 16 + (lane & 15);
            int k8 = (lane >> 4) * 8;
            bh[ct] = *(bf16x8*)(Ph + n * RS + k8);
            bl[ct] = *(bf16x8*)(Pl + n * RS + k8);
        }
#pragma unroll
        for (int rt = 0; rt < 4; ++rt)
#pragma unroll
            for (int ct = 0; ct < 4; ++ct) {
                acc[rt][ct] = __builtin_amdgcn_mfma_f32_16x16x32_bf16(ah[rt], bh[ct], acc[rt][ct], 0, 0, 0);
                acc[rt][ct] = __builtin_amdgcn_mfma_f32_16x16x32_bf16(ah[rt], bl[ct], acc[rt][ct], 0, 0, 0);
                acc[rt][ct] = __builtin_amdgcn_mfma_f32_16x16x32_bf16(al[rt], bh[ct], acc[rt][ct], 0, 0, 0);
            }
    }
    // reduce t partials: t[s] = sum over 16 c-groups
    if (MODE != 2) {
#pragma unroll
        for (int i = 0; i < 4; ++i) tred[cg * 64 + pos + i] = tp[i];
    }
    __syncthreads();
    if (MODE != 2 && tid < 64) {
        float s = 0.f;
#pragma unroll
        for (int g = 0; g < 16; ++g) s += tred[g * 64 + tid];
        ts[tid] = s;
    }
    __syncthreads();
    // epilogue: C/D layout col=lane&15, row=(lane>>4)*4+reg
#pragma unroll
    for (int rt = 0; rt < 4; ++rt)
#pragma unroll
        for (int ct = 0; ct < 4; ++ct) {
            int sl = ct * 16 + (lane & 15);
            int s = sbase + sl;
            int r0 = mbase + rt * 16 + (lane >> 4) * 4;
            float tv = (MODE == 2) ? 0.f : ts[sl];
#pragma unroll
            for (int reg = 0; reg < 4; ++reg) {
                size_t idx = boff + (size_t)(r0 + reg) * HWn + s;
                float g = acc[rt][ct][reg];
                if (MODE == 2) wout[idx] = g;
                else wout[idx] = g - Zb[idx] * tv;
            }
        }
}

// ============ dots (CGS): D[k][j] = <U_j, w>, j=0..NU-1 (j=0: fp32 v) ============
template <int NU>
__global__ __launch_bounds__(256) void dots_kernel(const float* __restrict__ w,
                                                   const float* __restrict__ v,
                                                   const unsigned short* __restrict__ Qb,
                                                   float* __restrict__ acc, int k) {
    const int b = blockIdx.y;
    const size_t boff = (size_t)b * FB;
    const float4* wv = (const float4*)(w + boff);
    const float4* vv = (const float4*)(v + boff);
    const uint4* uv[NU];
#pragma unroll
    for (int j = 1; j < NU; ++j)
        uv[j] = (const uint4*)(Qb + (size_t)(j - 1) * NTOT + boff);
    int i = blockIdx.x * 256 + threadIdx.x;
    float p[NU];
#pragma unroll
    for (int j = 0; j < NU; ++j) p[j] = 0.f;
#pragma unroll
    for (int r = 0; r < 2; ++r) {
        int idx = i + r * 65536;
        float4 w0 = wv[2 * idx], w1 = wv[2 * idx + 1];
        float we[8] = {w0.x, w0.y, w0.z, w0.w, w1.x, w1.y, w1.z, w1.w};
        float4 v0 = vv[2 * idx], v1 = vv[2 * idx + 1];
        float ve[8] = {v0.x, v0.y, v0.z, v0.w, v1.x, v1.y, v1.z, v1.w};
#pragma unroll
        for (int e = 0; e < 8; ++e) p[0] = fmaf(ve[e], we[e], p[0]);
#pragma unroll
        for (int j = 1; j < NU; ++j) {
            uint4 u = uv[j][idx];
            float ue[8]; unp8(u, ue);
#pragma unroll
            for (int e = 0; e < 8; ++e) p[j] = fmaf(ue[e], we[e], p[j]);
        }
    }
    __shared__ float red[4][NU];
    int lane = threadIdx.x & 63, wid = threadIdx.x >> 6;
#pragma unroll
    for (int j = 0; j < NU; ++j) {
        float q = p[j];
        for (int off = 32; off > 0; off >>= 1) q += __shfl_down(q, off);
        if (lane == 0) red[wid][j] = q;
    }
    __syncthreads();
    if (threadIdx.x < NU)
        atomicAdd(&acc[(k * 8 + threadIdx.x) * 8 + b],
                  red[0][threadIdx.x] + red[1][threadIdx.x] +
                  red[2][threadIdx.x] + red[3][threadIdx.x]);
}

// ============ update: U_K = w - sum_{j<K} c_j U_j (bf16 store); Nsq[K] ============
template <int K>
__global__ __launch_bounds__(256) void update_kernel(const float* __restrict__ w,
                                                     const float* __restrict__ v,
                                                     unsigned short* __restrict__ Qb,
                                                     float* __restrict__ acc) {
    const int b = blockIdx.y;
    const size_t boff = (size_t)b * FB;
    float cj[K];
    {
        float m[K];
        m[0] = sqrtf(acc[512 + b]);
#pragma unroll
        for (int j = 1; j < K; ++j) m[j] = sqrtf(acc[512 + j * 8 + b]) + EPSK * m[j - 1];
#pragma unroll
        for (int j = 0; j < K; ++j)
            cj[j] = acc[((K - 1) * 8 + j) * 8 + b] / (m[j] * m[j]);
    }
    const float4* wv = (const float4*)(w + boff);
    const float4* vv = (const float4*)(v + boff);
    const uint4* uv[K > 1 ? K : 2];
#pragma unroll
    for (int j = 1; j < K; ++j)
        uv[j] = (const uint4*)((const unsigned short*)Qb + (size_t)(j - 1) * NTOT + boff);
    uint4* Uk = (uint4*)(Qb + (size_t)(K - 1) * NTOT + boff);
    int i = blockIdx.x * 256 + threadIdx.x;
    float np = 0.f;
#pragma unroll
    for (int r = 0; r < 2; ++r) {
        int idx = i + r * 65536;
        float4 w0 = wv[2 * idx], w1 = wv[2 * idx + 1];
        float x[8] = {w0.x, w0.y, w0.z, w0.w, w1.x, w1.y, w1.z, w1.w};
        float4 v0 = vv[2 * idx], v1 = vv[2 * idx + 1];
        float ve[8] = {v0.x, v0.y, v0.z, v0.w, v1.x, v1.y, v1.z, v1.w};
#pragma unroll
        for (int e = 0; e < 8; ++e) x[e] = fmaf(-cj[0], ve[e], x[e]);
#pragma unroll
        for (int j = 1; j < K; ++j) {
            uint4 u = uv[j][idx];
            float ue[8]; unp8(u, ue);
#pragma unroll
            for (int e = 0; e < 8; ++e) x[e] = fmaf(-cj[j], ue[e], x[e]);
        }
        unsigned int h[8];
#pragma unroll
        for (int e = 0; e < 8; ++e) h[e] = f2b(x[e]);
        uint4 o;
        o.x = h[0] | (h[1] << 16); o.y = h[2] | (h[3] << 16);
        o.z = h[4] | (h[5] << 16); o.w = h[6] | (h[7] << 16);
        Uk[idx] = o;
#pragma unroll
        for (int e = 0; e < 8; ++e) { float xr = b2f(h[e]); np = fmaf(xr, xr, np); }
    }
    for (int off = 32; off > 0; off >>= 1) np += __shfl_down(np, off);
    __shared__ float red[4];
    int lane = threadIdx.x & 63, wid = threadIdx.x >> 6;
    if (lane == 0) red[wid] = np;
    __syncthreads();
    if (threadIdx.x == 0)
        atomicAdd(&acc[512 + K * 8 + b], red[0] + red[1] + red[2] + red[3]);
}

// ---------------- expm of 9x9 per batch (fp64); emits combine coeffs ----------
__global__ __launch_bounds__(128) void expm_kernel(const float* __restrict__ acc,
                                                   float* __restrict__ coordsOut) {
    __shared__ double Am[81], Pm[81], Tm[81];
    __shared__ double ssc;
    __shared__ int sn;
    const int b = blockIdx.x;
    const int t = threadIdx.x;
    const int r = t / 9, c = t % 9;
    double m[8];
    m[0] = sqrt((double)acc[512 + b]);
    for (int j = 1; j < 8; ++j) m[j] = sqrt((double)acc[512 + j * 8 + b]) + 1e-12 * m[j - 1];
    if (t < 81) {
        double val = 0.0;
        if (r < 8 && c < 8) {
            if (r <= c) val = TEND * (double)acc[(c * 8 + r) * 8 + b] / (m[r] * m[c]);
            else if (r == c + 1) val = TEND * sqrt((double)acc[512 + r * 8 + b]) / m[c];
        }
        if (r == 0 && c == 8) val = TEND;
        Am[t] = val;
    }
    __syncthreads();
    if (t == 0) {
        double mx = 0.0;
        for (int rr = 0; rr < 9; ++rr) {
            double s = 0.0;
            for (int cc = 0; cc < 9; ++cc) s += fabs(Am[rr * 9 + cc]);
            if (s > mx) mx = s;
        }
        int n = 0;
        while (mx > 0.25 && n < 48) { mx *= 0.5; ++n; }
        double sc = 1.0;
        for (int ii = 0; ii < n; ++ii) sc *= 0.5;
        sn = n; ssc = sc;
    }
    __syncthreads();
    if (t < 81) Am[t] *= ssc;
    __syncthreads();
    if (t < 81) Pm[t] = (r == c) ? 1.0 : 0.0;
    __syncthreads();
    for (int i = 20; i >= 1; --i) {
        if (t < 81) {
            double s = 0.0;
            for (int k = 0; k < 9; ++k) s += Am[r * 9 + k] * Pm[k * 9 + c];
            Tm[t] = ((r == c) ? 1.0 : 0.0) + s / (double)i;
        }
        __syncthreads();
        if (t < 81) Pm[t] = Tm[t];
        __syncthreads();
    }
    int n = sn;
    for (int q = 0; q < n; ++q) {
        if (t < 81) {
            double s = 0.0;
            for (int k = 0; k < 9; ++k) s += Pm[r * 9 + k] * Pm[k * 9 + c];
            Tm[t] = s;
        }
        __syncthreads();
        if (t < 81) Pm[t] = Tm[t];
        __syncthreads();
    }
    if (t < 8) coordsOut[b * 8 + t] = (float)(Pm[t * 9 + 8] * m[0] / m[t]);
}

// ------ out = coeff_0*v + sum_{j=1..7} coeff_j * U_j (bf16) ------
__global__ __launch_bounds__(256) void combine_kernel(const unsigned short* __restrict__ Qb,
                                                      const float* __restrict__ v,
                                                      const float* __restrict__ coords,
                                                      float* __restrict__ out) {
    int b = blockIdx.y;
    const size_t boff = (size_t)b * FB;
    float cf[8];
#pragma unroll
    for (int j = 0; j < 8; ++j) cf[j] = coords[b * 8 + j];
    const float4* vv = (const float4*)(v + boff);
    const uint4* uv[8];
#pragma unroll
    for (int j = 1; j < 8; ++j)
        uv[j] = (const uint4*)(Qb + (size_t)(j - 1) * NTOT + boff);
    int i = blockIdx.x * 256 + threadIdx.x;
    float4* ov = (float4*)(out + boff);
#pragma unroll
    for (int r = 0; r < 2; ++r) {
        int idx = i + r * 65536;
        float4 v0 = vv[2 * idx], v1 = vv[2 * idx + 1];
        float a[8] = {cf[0] * v0.x, cf[0] * v0.y, cf[0] * v0.z, cf[0] * v0.w,
                      cf[0] * v1.x, cf[0] * v1.y, cf[0] * v1.z, cf[0] * v1.w};
#pragma unroll
        for (int j = 1; j < 8; ++j) {
            uint4 u = uv[j][idx];
            float ue[8]; unp8(u, ue);
#pragma unroll
            for (int e = 0; e < 8; ++e) a[e] = fmaf(cf[j], ue[e], a[e]);
        }
        float4 o0 = {a[0], a[1], a[2], a[3]};
        float4 o1 = {a[4], a[5], a[6], a[7]};
        ov[2 * idx] = o0; ov[2 * idx + 1] = o1;
    }
}

extern "C" void kernel_launch(void* const* d_in, const int* in_sizes, int n_in,
                              void* d_out, int out_size, void* d_ws, size_t ws_size,
                              hipStream_t stream) {
    const float* s0 = (const float*)d_in[0];
    const float* v  = (const float*)d_in[1];
    const float* W  = (const float*)d_in[2];
    float* out = (float*)d_out;

    // ws (floats): [acc 576 | coords 64 | pad->1024 | Whs 32768 | Wls 32768 | Z NTOT | Qb bf16 7*NTOT/2]
    float* ws     = (float*)d_ws;
    float* acc    = ws;
    float* coords = ws + 576;
    unsigned short* Whs = (unsigned short*)(ws + 1024);
    unsigned short* Wls = (unsigned short*)(ws + 1024 + 32768);
    float* Zb     = ws + 1024 + 65536;
    unsigned short* Qb = (unsigned short*)(Zb + NTOT);   // 7 bf16 fields
    float* w      = out;   // working A-output (fp32)

    init_kernel<<<dim3(1), dim3(256), 0, stream>>>(ws);
    wsplit_kernel<<<dim3(8, 16), dim3(64), 0, stream>>>(W, Whs, Wls);

    dim3 g(256, 8), blk(256), ga(64, 8);
    norm0_kernel<<<g, blk, 0, stream>>>(v, acc);
    // Z = W @ s0 (once)
    apply_mfma<2><<<ga, blk, 0, stream>>>(nullptr, nullptr, s0, Whs, Wls, nullptr, Zb);

    // K = 0
    apply_mfma<1><<<ga, blk, 0, stream>>>(nullptr, v, s0, Whs, Wls, Zb, w);
    dots_kernel<1><<<g, blk, 0, stream>>>(w, v, Qb, acc, 0);

#define STEP(K)                                                                       \
    update_kernel<K><<<g, blk, 0, stream>>>(w, v, Qb, acc);                           \
    apply_mfma<0><<<ga, blk, 0, stream>>>(Qb + (size_t)(K - 1) * NTOT, nullptr, s0,  \
                                          Whs, Wls, Zb, w);                           \
    dots_kernel<K + 1><<<g, blk, 0, stream>>>(w, v, Qb, acc, K);
    STEP(1) STEP(2) STEP(3) STEP(4) STEP(5) STEP(6) STEP(7)
#undef STEP

    expm_kernel<<<dim3(8), dim3(128), 0, stream>>>(acc, coords);
    combine_kernel<<<g, blk, 0, stream>>>(Qb, v, coords, out);
}